// Round 14
// baseline (73.996 us; speedup 1.0000x reference)
//
#include <hip/hip_runtime.h>
#include <hip/hip_bf16.h>
#include <math.h>

#define BB 8
#define SS 512
#define EE 128
#define HH 16
#define DKK 8

#define FMA4(ACC, S, W) do { (ACC).x += (S)*(W).x; (ACC).y += (S)*(W).y; \
                             (ACC).z += (S)*(W).z; (ACC).w += (S)*(W).w; } while(0)
#define ADD4(A, B) do { (A).x += (B).x; (A).y += (B).y; (A).z += (B).z; (A).w += (B).w; } while(0)
#define DOT4(A, B) ((A).x*(B).x + (A).y*(B).y + (A).z*(B).z + (A).w*(B).w)

// ---------------------------------------------------------------------------
// Kernel 1: QKV GEMM + bias + theta + quantum head; also initializes
// out = bo so kernel 2 can atomically accumulate head contributions.
// grid (256, 3); block 256 = 4 waves; per-lane tile 2 rows x 4 cols.
// x tile staged in LDS (8KB, broadcast b128 reads); W coalesced float4.
// launch_bounds(256,2): no forced 64-VGPR squeeze (actual ~55 -> same occ).
// Output layout (B, H, S, 8).
// ---------------------------------------------------------------------------
__global__ __launch_bounds__(256, 2) void k_qkvq(
    const float* __restrict__ x,
    const float* __restrict__ Wq, const float* __restrict__ bq,
    const float* __restrict__ Wk, const float* __restrict__ bk,
    const float* __restrict__ Wv, const float* __restrict__ bv,
    const float* __restrict__ theta, const float* __restrict__ bo,
    float* __restrict__ qh, float* __restrict__ kh, float* __restrict__ vh,
    float* __restrict__ out)
{
    __shared__ float xs[16][128];
    const int t = threadIdx.x;
    const int m = blockIdx.y;
    const int row0 = blockIdx.x * 16;

    {
        const float4* xv = (const float4*)(x + (size_t)row0 * 128);
        float4* xsv = (float4*)&xs[0][0];
        xsv[t]       = xv[t];
        xsv[t + 256] = xv[t + 256];
    }
    __syncthreads();

    const int cg   = t & 31;
    const int col0 = cg * 4;
    const int rg   = t >> 5;
    const int r0   = rg * 2;

    const float* __restrict__ W  = (m == 0) ? Wq : (m == 1) ? Wk : Wv;
    const float* __restrict__ bb = (m == 0) ? bq : (m == 1) ? bk : bv;
    float* __restrict__ outp     = (m == 0) ? qh : (m == 1) ? kh : vh;

    float4 acc0 = *(const float4*)&bb[col0];
    float4 acc1 = acc0;

    #pragma unroll 4
    for (int k4 = 0; k4 < 32; ++k4) {
        const float4 xa = ((const float4*)xs[r0 + 0])[k4];
        const float4 xb = ((const float4*)xs[r0 + 1])[k4];
        const float4 w0 = *(const float4*)&W[(k4 * 4 + 0) * 128 + col0];
        const float4 w1 = *(const float4*)&W[(k4 * 4 + 1) * 128 + col0];
        const float4 w2 = *(const float4*)&W[(k4 * 4 + 2) * 128 + col0];
        const float4 w3 = *(const float4*)&W[(k4 * 4 + 3) * 128 + col0];
        FMA4(acc0, xa.x, w0); FMA4(acc0, xa.y, w1);
        FMA4(acc0, xa.z, w2); FMA4(acc0, xa.w, w3);
        FMA4(acc1, xb.x, w0); FMA4(acc1, xb.y, w1);
        FMA4(acc1, xb.z, w2); FMA4(acc1, xb.w, w3);
    }

    const float4 th = *(const float4*)&theta[col0];
    const int h    = cg >> 1;
    const int half = cg & 1;

    float4 accs[2] = {acc0, acc1};
    #pragma unroll
    for (int r = 0; r < 2; ++r) {
        float4 c;
        c.x = __cosf(accs[r].x + th.x);
        c.y = __cosf(accs[r].y + th.y);
        c.z = __cosf(accs[r].z + th.z);
        c.w = __cosf(accs[r].w + th.w);
        const float p0 = c.x;
        const float p1 = p0 * c.y;
        const float p2 = p1 * c.z;
        const float p3 = p2 * c.w;
        const float recv = __shfl_xor(p3, 1);
        float4 o;
        if (half == 0) {
            o.x = c.y * c.z * c.w * recv;  // wire 0: c1..c7
            o.y = p1; o.z = p2; o.w = p3;  // wires 1-3: c0..cw
        } else {
            o.x = recv * p0;               // wires 4-7: (c0..c3)*(c4..cw)
            o.y = recv * p1;
            o.z = recv * p2;
            o.w = recv * p3;
        }
        const int g  = row0 + r0 + r;
        const int b_ = g >> 9;
        const int s  = g & 511;
        *(float4*)&outp[(((size_t)b_ * HH + h) * SS + s) * DKK + half * 4] = o;
    }

    // initialize out = bo (once: only the m==0 grid slice)
    if (m == 0) {
        const float4 b0 = *(const float4*)&bo[col0];
        *(float4*)&out[(size_t)(row0 + r0 + 0) * 128 + col0] = b0;
        *(float4*)&out[(size_t)(row0 + r0 + 1) * 128 + col0] = b0;
    }
}

// ---------------------------------------------------------------------------
// Kernel 2: attention + fused output projection (atomic accumulate).
// grid 256 = (bh 0..127) x (q-half 0..1); block 512 = 8 waves;
// launch_bounds(512,2) -> VGPR cap 256, no spill (R12 lesson).
// LDS 56KB: [slots 4x256x3 f4 = 48KB | red 256x8 f = 8KB]; K/V stage
// (32KB) lives inside the slot region and is dead before combine.
// Wave wv = j-slice [wv*64,+64); lane owns R=4 q rows (L+64r). q pre-scaled
// by log2(e)/sqrt(8) -> exp2f. Single-pass softmax (bounded scores).
// Combine -> normalize -> red; then out-proj: lane = column (coalesced),
// rows broadcast from red, attnout @ Wo_h added into out with fp32 HW
// atomics (out pre-initialized to bo by kernel 1). No hid round-trip.
// ---------------------------------------------------------------------------
__global__ __launch_bounds__(512, 2) void k_attn_out(
    const float* __restrict__ qh, const float* __restrict__ kh,
    const float* __restrict__ vh, const float* __restrict__ Wo,
    float* __restrict__ out)
{
    __shared__ float4 smem[3584];     // 56KB: slots [0,3072) | red [3072,3584)

    const int t  = threadIdx.x;       // 0..511
    const int L  = t & 63;
    const int wv = t >> 6;            // 0..7
    const int bh = blockIdx.x & 127;
    const int q0 = (blockIdx.x >> 7) * 256;   // 0 or 256
    const int b_ = bh >> 4;
    const int h  = bh & 15;

    // stage K/V (2048 f4; 4 per thread, coalesced) into slot region
    {
        const float4* kg = (const float4*)kh + (size_t)bh * 1024;
        const float4* vg = (const float4*)vh + (size_t)bh * 1024;
        smem[t]        = kg[t];
        smem[t + 512]  = kg[t + 512];
        smem[1024 + t] = vg[t];
        smem[1536 + t] = vg[t + 512];
    }

    // lane's 4 q rows, pre-scaled so exp2f(s) == exp(q.k/sqrt(8))
    const float sc = 0.51012091944f;  // log2(e)/sqrt(8)
    float4 qa[4], qb[4];
    {
        const float4* qg = (const float4*)qh + ((size_t)bh * 512 + q0) * 2;
        #pragma unroll
        for (int r = 0; r < 4; ++r) {
            float4 a = qg[(L + 64 * r) * 2];
            float4 b = qg[(L + 64 * r) * 2 + 1];
            a.x *= sc; a.y *= sc; a.z *= sc; a.w *= sc;
            b.x *= sc; b.y *= sc; b.z *= sc; b.w *= sc;
            qa[r] = a; qb[r] = b;
        }
    }
    __syncthreads();

    float4 aA[4], aB[4];
    float  den[4];
    #pragma unroll
    for (int r = 0; r < 4; ++r) {
        aA[r] = make_float4(0.f, 0.f, 0.f, 0.f);
        aB[r] = make_float4(0.f, 0.f, 0.f, 0.f);
        den[r] = 0.f;
    }

    const float4* kbase = smem + wv * 128;          // this wave's 64 j rows
    const float4* vbase = smem + 1024 + wv * 128;

    #pragma unroll 4
    for (int j = 0; j < 64; ++j) {
        const float4 k0 = kbase[2 * j];
        const float4 k1 = kbase[2 * j + 1];
        const float4 v0 = vbase[2 * j];
        const float4 v1 = vbase[2 * j + 1];
        #pragma unroll
        for (int r = 0; r < 4; ++r) {
            const float s = DOT4(qa[r], k0) + DOT4(qb[r], k1);
            const float e = exp2f(s);
            den[r] += e;
            FMA4(aA[r], e, v0);
            FMA4(aB[r], e, v1);
        }
    }
    __syncthreads();    // all waves done reading the stage

    // combine: slots [4][256][3] f4; waves 0-3 write, 4-7 add
    if (wv < 4) {
        #pragma unroll
        for (int r = 0; r < 4; ++r) {
            const int idx = (wv * 256 + L + 64 * r) * 3;
            smem[idx]     = aA[r];
            smem[idx + 1] = aB[r];
            smem[idx + 2] = make_float4(den[r], 0.f, 0.f, 0.f);
        }
    }
    __syncthreads();
    if (wv >= 4) {
        #pragma unroll
        for (int r = 0; r < 4; ++r) {
            const int idx = ((wv - 4) * 256 + L + 64 * r) * 3;
            float4 pa = smem[idx];
            float4 pb = smem[idx + 1];
            float4 pd = smem[idx + 2];
            ADD4(pa, aA[r]); ADD4(pb, aB[r]); pd.x += den[r];
            smem[idx]     = pa;
            smem[idx + 1] = pb;
            smem[idx + 2] = pd;
        }
    }
    __syncthreads();

    // final 4-way reduce + normalize -> red (disjoint region, no race)
    if (t < 256) {
        float4 rA = make_float4(0.f, 0.f, 0.f, 0.f), rB = rA;
        float rd = 0.f;
        #pragma unroll
        for (int s4 = 0; s4 < 4; ++s4) {
            const int idx = (s4 * 256 + t) * 3;
            const float4 a = smem[idx];
            const float4 b = smem[idx + 1];
            ADD4(rA, a); ADD4(rB, b);
            rd += smem[idx + 2].x;
        }
        const float inv = 1.0f / rd;
        rA.x *= inv; rA.y *= inv; rA.z *= inv; rA.w *= inv;
        rB.x *= inv; rB.y *= inv; rB.z *= inv; rB.w *= inv;
        smem[3072 + t * 2]     = rA;
        smem[3072 + t * 2 + 1] = rB;
    }
    __syncthreads();

    // fused output projection: red(256x8) @ Wo_h(8x128), atomic accumulate.
    // lane = column (coalesced atomics); rows broadcast from red.
    {
        const int col = t & 127;
        const int rg  = t >> 7;          // 0..3 -> rows rg*64..rg*64+63
        float wo[8];
        #pragma unroll
        for (int i = 0; i < 8; ++i)
            wo[i] = Wo[(h * 8 + i) * 128 + col];

        const float* red = (const float*)(smem + 3072);
        float* obase = out + ((size_t)(b_ * 512) + q0 + rg * 64) * 128 + col;
        #pragma unroll 4
        for (int rr = 0; rr < 64; ++rr) {
            const float4 r0v = *(const float4*)&red[(rg * 64 + rr) * 8];
            const float4 r1v = *(const float4*)&red[(rg * 64 + rr) * 8 + 4];
            const float acc = r0v.x*wo[0] + r0v.y*wo[1] + r0v.z*wo[2] + r0v.w*wo[3]
                            + r1v.x*wo[4] + r1v.y*wo[5] + r1v.z*wo[6] + r1v.w*wo[7];
            unsafeAtomicAdd(obase + (size_t)rr * 128, acc);
        }
    }
}

// ---------------------------------------------------------------------------
extern "C" void kernel_launch(void* const* d_in, const int* in_sizes, int n_in,
                              void* d_out, int out_size, void* d_ws, size_t ws_size,
                              hipStream_t stream)
{
    const float* x     = (const float*)d_in[0];
    const float* Wq    = (const float*)d_in[1];
    const float* bq    = (const float*)d_in[2];
    const float* Wk    = (const float*)d_in[3];
    const float* bk    = (const float*)d_in[4];
    const float* Wv    = (const float*)d_in[5];
    const float* bv    = (const float*)d_in[6];
    const float* Wo    = (const float*)d_in[7];
    const float* bo    = (const float*)d_in[8];
    const float* theta = (const float*)d_in[9];
    float* out = (float*)d_out;

    float* ws = (float*)d_ws;
    float* qh = ws;                    // B*H*S*8 = 524288 floats each
    float* kh = ws + 524288;
    float* vh = ws + 1048576;

    k_qkvq<<<dim3(256, 3), 256, 0, stream>>>(x, Wq, bq, Wk, bk, Wv, bv,
                                             theta, bo, qh, kh, vh, out);
    k_attn_out<<<256, 512, 0, stream>>>(qh, kh, vh, Wo, out);
}

// Round 15
// 57.495 us; speedup vs baseline: 1.2870x; 1.2870x over previous
//
#include <hip/hip_runtime.h>
#include <hip/hip_bf16.h>
#include <math.h>

#define BB 8
#define SS 512
#define EE 128
#define HH 16
#define DKK 8

#define FMA4(ACC, S, W) do { (ACC).x += (S)*(W).x; (ACC).y += (S)*(W).y; \
                             (ACC).z += (S)*(W).z; (ACC).w += (S)*(W).w; } while(0)
#define ADD4(A, B) do { (A).x += (B).x; (A).y += (B).y; (A).z += (B).z; (A).w += (B).w; } while(0)
#define DOT4(A, B) ((A).x*(B).x + (A).y*(B).y + (A).z*(B).z + (A).w*(B).w)

// ---------------------------------------------------------------------------
// Kernel 1: QKV GEMM + bias + theta + quantum head (R13-proven, unchanged).
// grid (256, 3); block 256 = 4 waves; per-lane tile 2 rows x 4 cols.
// x tile staged in LDS (8KB, broadcast b128 reads); W coalesced float4.
// Output layout (B, H, S, 8).
// ---------------------------------------------------------------------------
__global__ __launch_bounds__(256, 4) void k_qkvq(
    const float* __restrict__ x,
    const float* __restrict__ Wq, const float* __restrict__ bq,
    const float* __restrict__ Wk, const float* __restrict__ bk,
    const float* __restrict__ Wv, const float* __restrict__ bv,
    const float* __restrict__ theta,
    float* __restrict__ qh, float* __restrict__ kh, float* __restrict__ vh)
{
    __shared__ float xs[16][128];
    const int t = threadIdx.x;
    const int m = blockIdx.y;
    const int row0 = blockIdx.x * 16;

    {
        const float4* xv = (const float4*)(x + (size_t)row0 * 128);
        float4* xsv = (float4*)&xs[0][0];
        xsv[t]       = xv[t];
        xsv[t + 256] = xv[t + 256];
    }
    __syncthreads();

    const int cg   = t & 31;
    const int col0 = cg * 4;
    const int rg   = t >> 5;
    const int r0   = rg * 2;

    const float* __restrict__ W  = (m == 0) ? Wq : (m == 1) ? Wk : Wv;
    const float* __restrict__ bb = (m == 0) ? bq : (m == 1) ? bk : bv;
    float* __restrict__ outp     = (m == 0) ? qh : (m == 1) ? kh : vh;

    float4 acc0 = *(const float4*)&bb[col0];
    float4 acc1 = acc0;

    #pragma unroll 4
    for (int k4 = 0; k4 < 32; ++k4) {
        const float4 xa = ((const float4*)xs[r0 + 0])[k4];
        const float4 xb = ((const float4*)xs[r0 + 1])[k4];
        const float4 w0 = *(const float4*)&W[(k4 * 4 + 0) * 128 + col0];
        const float4 w1 = *(const float4*)&W[(k4 * 4 + 1) * 128 + col0];
        const float4 w2 = *(const float4*)&W[(k4 * 4 + 2) * 128 + col0];
        const float4 w3 = *(const float4*)&W[(k4 * 4 + 3) * 128 + col0];
        FMA4(acc0, xa.x, w0); FMA4(acc0, xa.y, w1);
        FMA4(acc0, xa.z, w2); FMA4(acc0, xa.w, w3);
        FMA4(acc1, xb.x, w0); FMA4(acc1, xb.y, w1);
        FMA4(acc1, xb.z, w2); FMA4(acc1, xb.w, w3);
    }

    const float4 th = *(const float4*)&theta[col0];
    const int h    = cg >> 1;
    const int half = cg & 1;

    float4 accs[2] = {acc0, acc1};
    #pragma unroll
    for (int r = 0; r < 2; ++r) {
        float4 c;
        c.x = __cosf(accs[r].x + th.x);
        c.y = __cosf(accs[r].y + th.y);
        c.z = __cosf(accs[r].z + th.z);
        c.w = __cosf(accs[r].w + th.w);
        const float p0 = c.x;
        const float p1 = p0 * c.y;
        const float p2 = p1 * c.z;
        const float p3 = p2 * c.w;
        const float recv = __shfl_xor(p3, 1);
        float4 o;
        if (half == 0) {
            o.x = c.y * c.z * c.w * recv;  // wire 0: c1..c7
            o.y = p1; o.z = p2; o.w = p3;  // wires 1-3: c0..cw
        } else {
            o.x = recv * p0;               // wires 4-7: (c0..c3)*(c4..cw)
            o.y = recv * p1;
            o.z = recv * p2;
            o.w = recv * p3;
        }
        const int g  = row0 + r0 + r;
        const int b_ = g >> 9;
        const int s  = g & 511;
        *(float4*)&outp[(((size_t)b_ * HH + h) * SS + s) * DKK + half * 4] = o;
    }
}

// ---------------------------------------------------------------------------
// Kernel 2: attention, R=8 q-rows/lane via HALF-WAVE j-split.
// grid 256 = (bh 0..127) x (q-half 0..1); block 512 = 8 waves, 48KB LDS.
// Full K+V (32KB) staged. Lane (wv, hw=L>>5, l5=L&31) covers j-slice
// [wv*64 + hw*32, +32) for rows l5+32r, r=0..7. The LDS broadcast read now
// serves 2 addresses per instr (half-waves read different j) — 2-way access
// is free (m136) — so total ds_read count HALVES vs R=4 (10.2 -> 5.1us
// chip LDS-pipe), and 8 independent q-row chains double the ILP.
// q pre-scaled by log2(e)/sqrt(8) -> exp2f. Single-pass softmax (|s|<=4.1).
// Half-wave partials merged via __shfl_xor(32); then R13's slot combine
// (4 slots x 256 x 3 f4 = 48KB, unioned with dead stage); normalize; write.
// __launch_bounds__(512) one-arg: allocator free to use up to 256 VGPRs
// (need ~170; R12-R14's 56-64-VGPR squeeze was the hidden spill killer).
// ---------------------------------------------------------------------------
__global__ __launch_bounds__(512) void k_attn(
    const float* __restrict__ qh, const float* __restrict__ kh,
    const float* __restrict__ vh, float* __restrict__ hid)
{
    __shared__ float4 smem[3072];     // 48KB: stage (2048 f4) / combine (3072)

    const int t  = threadIdx.x;       // 0..511
    const int L  = t & 63;
    const int wv = t >> 6;            // 0..7
    const int hw = L >> 5;            // half-wave 0/1
    const int l5 = L & 31;
    const int bh = blockIdx.x & 127;
    const int q0 = (blockIdx.x >> 7) * 256;   // 0 or 256

    // stage K/V (2048 f4; 4 per thread, coalesced)
    {
        const float4* kg = (const float4*)kh + (size_t)bh * 1024;
        const float4* vg = (const float4*)vh + (size_t)bh * 1024;
        smem[t]        = kg[t];
        smem[t + 512]  = kg[t + 512];
        smem[1024 + t] = vg[t];
        smem[1536 + t] = vg[t + 512];
    }

    // lane's 8 q rows (l5 + 32r), pre-scaled so exp2f(s) == exp(q.k/sqrt(8))
    const float sc = 0.51012091944f;  // log2(e)/sqrt(8)
    float4 qa[8], qb[8];
    {
        const float4* qg = (const float4*)qh + ((size_t)bh * 512 + q0) * 2;
        #pragma unroll
        for (int r = 0; r < 8; ++r) {
            float4 a = qg[(l5 + 32 * r) * 2];
            float4 b = qg[(l5 + 32 * r) * 2 + 1];
            a.x *= sc; a.y *= sc; a.z *= sc; a.w *= sc;
            b.x *= sc; b.y *= sc; b.z *= sc; b.w *= sc;
            qa[r] = a; qb[r] = b;
        }
    }
    __syncthreads();

    float4 aA[8], aB[8];
    float  den[8];
    #pragma unroll
    for (int r = 0; r < 8; ++r) {
        aA[r] = make_float4(0.f, 0.f, 0.f, 0.f);
        aB[r] = make_float4(0.f, 0.f, 0.f, 0.f);
        den[r] = 0.f;
    }

    // this (wave, half-wave)'s 32 j rows
    const float4* kbase = smem + wv * 128 + hw * 64;
    const float4* vbase = smem + 1024 + wv * 128 + hw * 64;

    #pragma unroll 4
    for (int jj = 0; jj < 32; ++jj) {
        const float4 k0 = kbase[2 * jj];
        const float4 k1 = kbase[2 * jj + 1];
        const float4 v0 = vbase[2 * jj];
        const float4 v1 = vbase[2 * jj + 1];
        #pragma unroll
        for (int r = 0; r < 8; ++r) {
            const float s = DOT4(qa[r], k0) + DOT4(qb[r], k1);
            const float e = exp2f(s);
            den[r] += e;
            FMA4(aA[r], e, v0);
            FMA4(aB[r], e, v1);
        }
    }

    // merge half-wave j-partials (lanes l5 and l5+32 hold the same rows)
    #pragma unroll
    for (int r = 0; r < 8; ++r) {
        aA[r].x += __shfl_xor(aA[r].x, 32); aA[r].y += __shfl_xor(aA[r].y, 32);
        aA[r].z += __shfl_xor(aA[r].z, 32); aA[r].w += __shfl_xor(aA[r].w, 32);
        aB[r].x += __shfl_xor(aB[r].x, 32); aB[r].y += __shfl_xor(aB[r].y, 32);
        aB[r].z += __shfl_xor(aB[r].z, 32); aB[r].w += __shfl_xor(aB[r].w, 32);
        den[r]  += __shfl_xor(den[r], 32);
    }
    __syncthreads();    // stage dead; smem becomes combine buffer

    // slot combine: slots [4][256][3] f4; lane writes rows r = hw*4..hw*4+3
    if (wv < 4) {
        #pragma unroll
        for (int rr = 0; rr < 4; ++rr) {
            const int r   = hw * 4 + rr;
            const int row = l5 + 32 * r;
            const int idx = (wv * 256 + row) * 3;
            smem[idx]     = aA[r];
            smem[idx + 1] = aB[r];
            smem[idx + 2] = make_float4(den[r], 0.f, 0.f, 0.f);
        }
    }
    __syncthreads();
    if (wv >= 4) {
        #pragma unroll
        for (int rr = 0; rr < 4; ++rr) {
            const int r   = hw * 4 + rr;
            const int row = l5 + 32 * r;
            const int idx = ((wv - 4) * 256 + row) * 3;
            float4 pa = smem[idx];
            float4 pb = smem[idx + 1];
            float4 pd = smem[idx + 2];
            ADD4(pa, aA[r]); ADD4(pb, aB[r]); pd.x += den[r];
            smem[idx]     = pa;
            smem[idx + 1] = pb;
            smem[idx + 2] = pd;
        }
    }
    __syncthreads();

    // final 4-way reduce + normalize + write (row-major hid)
    if (t < 256) {
        float4 rA = make_float4(0.f, 0.f, 0.f, 0.f), rB = rA;
        float rd = 0.f;
        #pragma unroll
        for (int s4 = 0; s4 < 4; ++s4) {
            const int idx = (s4 * 256 + t) * 3;
            const float4 a = smem[idx];
            const float4 b = smem[idx + 1];
            ADD4(rA, a); ADD4(rB, b);
            rd += smem[idx + 2].x;
        }
        const float inv = 1.0f / rd;
        rA.x *= inv; rA.y *= inv; rA.z *= inv; rA.w *= inv;
        rB.x *= inv; rB.y *= inv; rB.z *= inv; rB.w *= inv;
        const int b_ = bh >> 4, h = bh & 15;
        float* o = hid + ((size_t)(b_ * 512) + q0 + t) * 128 + h * 8;
        ((float4*)o)[0] = rA;
        ((float4*)o)[1] = rB;
    }
}

// ---------------------------------------------------------------------------
// Kernel 3: output projection hid(4096x128, row-major) @ Wo(128x128) + bo.
// grid 256 x 256: 16 rows/block (R13-proven, unchanged).
// ---------------------------------------------------------------------------
__global__ __launch_bounds__(256, 4) void k_out(
    const float* __restrict__ hid, const float* __restrict__ Wo,
    const float* __restrict__ bo, float* __restrict__ out)
{
    __shared__ float hs[16][128];
    const int t = threadIdx.x;
    const int row0 = blockIdx.x * 16;

    {
        const float4* hv = (const float4*)(hid + (size_t)row0 * 128);
        float4* hsv = (float4*)&hs[0][0];
        hsv[t]       = hv[t];
        hsv[t + 256] = hv[t + 256];
    }
    __syncthreads();

    const int cg   = t & 31;
    const int col0 = cg * 4;
    const int rg   = t >> 5;
    const int r0   = rg * 2;

    float4 acc0 = *(const float4*)&bo[col0];
    float4 acc1 = acc0;

    #pragma unroll 4
    for (int k4 = 0; k4 < 32; ++k4) {
        const float4 xa = ((const float4*)hs[r0 + 0])[k4];
        const float4 xb = ((const float4*)hs[r0 + 1])[k4];
        const float4 w0 = *(const float4*)&Wo[(k4 * 4 + 0) * 128 + col0];
        const float4 w1 = *(const float4*)&Wo[(k4 * 4 + 1) * 128 + col0];
        const float4 w2 = *(const float4*)&Wo[(k4 * 4 + 2) * 128 + col0];
        const float4 w3 = *(const float4*)&Wo[(k4 * 4 + 3) * 128 + col0];
        FMA4(acc0, xa.x, w0); FMA4(acc0, xa.y, w1);
        FMA4(acc0, xa.z, w2); FMA4(acc0, xa.w, w3);
        FMA4(acc1, xb.x, w0); FMA4(acc1, xb.y, w1);
        FMA4(acc1, xb.z, w2); FMA4(acc1, xb.w, w3);
    }

    *(float4*)&out[(size_t)(row0 + r0 + 0) * 128 + col0] = acc0;
    *(float4*)&out[(size_t)(row0 + r0 + 1) * 128 + col0] = acc1;
}

// ---------------------------------------------------------------------------
extern "C" void kernel_launch(void* const* d_in, const int* in_sizes, int n_in,
                              void* d_out, int out_size, void* d_ws, size_t ws_size,
                              hipStream_t stream)
{
    const float* x     = (const float*)d_in[0];
    const float* Wq    = (const float*)d_in[1];
    const float* bq    = (const float*)d_in[2];
    const float* Wk    = (const float*)d_in[3];
    const float* bk    = (const float*)d_in[4];
    const float* Wv    = (const float*)d_in[5];
    const float* bv    = (const float*)d_in[6];
    const float* Wo    = (const float*)d_in[7];
    const float* bo    = (const float*)d_in[8];
    const float* theta = (const float*)d_in[9];
    float* out = (float*)d_out;

    float* ws  = (float*)d_ws;
    float* qh  = ws;                   // B*H*S*8 = 524288 floats each
    float* kh  = ws + 524288;
    float* vh  = ws + 1048576;
    float* hid = ws + 1572864;         // row-major (B,S,E)

    k_qkvq<<<dim3(256, 3), 256, 0, stream>>>(x, Wq, bq, Wk, bk, Wv, bv,
                                             theta, qh, kh, vh);
    k_attn<<<256, 512, 0, stream>>>(qh, kh, vh, hid);
    k_out <<<256, 256, 0, stream>>>(hid, Wo, bo, out);
}

// Round 16
// 47.809 us; speedup vs baseline: 1.5477x; 1.2026x over previous
//
#include <hip/hip_runtime.h>
#include <hip/hip_bf16.h>
#include <math.h>

#define BB 8
#define SS 512
#define EE 128
#define HH 16
#define DKK 8

#define FMA4(ACC, S, W) do { (ACC).x += (S)*(W).x; (ACC).y += (S)*(W).y; \
                             (ACC).z += (S)*(W).z; (ACC).w += (S)*(W).w; } while(0)
#define ADD4(A, B) do { (A).x += (B).x; (A).y += (B).y; (A).z += (B).z; (A).w += (B).w; } while(0)
#define DOT4(A, B) ((A).x*(B).x + (A).y*(B).y + (A).z*(B).z + (A).w*(B).w)

// ---------------------------------------------------------------------------
// Kernel 1: QKV GEMM + bias + theta + quantum head (R13-proven, unchanged).
// grid (256, 3); block 256 = 4 waves; per-lane tile 2 rows x 4 cols.
// x tile staged in LDS (8KB, broadcast b128 reads); W coalesced float4.
// Output layout (B, H, S, 8). Live state ~55 regs, no spill at 64-cap.
// ---------------------------------------------------------------------------
__global__ __launch_bounds__(256, 4) void k_qkvq(
    const float* __restrict__ x,
    const float* __restrict__ Wq, const float* __restrict__ bq,
    const float* __restrict__ Wk, const float* __restrict__ bk,
    const float* __restrict__ Wv, const float* __restrict__ bv,
    const float* __restrict__ theta,
    float* __restrict__ qh, float* __restrict__ kh, float* __restrict__ vh)
{
    __shared__ float xs[16][128];
    const int t = threadIdx.x;
    const int m = blockIdx.y;
    const int row0 = blockIdx.x * 16;

    {
        const float4* xv = (const float4*)(x + (size_t)row0 * 128);
        float4* xsv = (float4*)&xs[0][0];
        xsv[t]       = xv[t];
        xsv[t + 256] = xv[t + 256];
    }
    __syncthreads();

    const int cg   = t & 31;
    const int col0 = cg * 4;
    const int rg   = t >> 5;
    const int r0   = rg * 2;

    const float* __restrict__ W  = (m == 0) ? Wq : (m == 1) ? Wk : Wv;
    const float* __restrict__ bb = (m == 0) ? bq : (m == 1) ? bk : bv;
    float* __restrict__ outp     = (m == 0) ? qh : (m == 1) ? kh : vh;

    float4 acc0 = *(const float4*)&bb[col0];
    float4 acc1 = acc0;

    #pragma unroll 4
    for (int k4 = 0; k4 < 32; ++k4) {
        const float4 xa = ((const float4*)xs[r0 + 0])[k4];
        const float4 xb = ((const float4*)xs[r0 + 1])[k4];
        const float4 w0 = *(const float4*)&W[(k4 * 4 + 0) * 128 + col0];
        const float4 w1 = *(const float4*)&W[(k4 * 4 + 1) * 128 + col0];
        const float4 w2 = *(const float4*)&W[(k4 * 4 + 2) * 128 + col0];
        const float4 w3 = *(const float4*)&W[(k4 * 4 + 3) * 128 + col0];
        FMA4(acc0, xa.x, w0); FMA4(acc0, xa.y, w1);
        FMA4(acc0, xa.z, w2); FMA4(acc0, xa.w, w3);
        FMA4(acc1, xb.x, w0); FMA4(acc1, xb.y, w1);
        FMA4(acc1, xb.z, w2); FMA4(acc1, xb.w, w3);
    }

    const float4 th = *(const float4*)&theta[col0];
    const int h    = cg >> 1;
    const int half = cg & 1;

    float4 accs[2] = {acc0, acc1};
    #pragma unroll
    for (int r = 0; r < 2; ++r) {
        float4 c;
        c.x = __cosf(accs[r].x + th.x);
        c.y = __cosf(accs[r].y + th.y);
        c.z = __cosf(accs[r].z + th.z);
        c.w = __cosf(accs[r].w + th.w);
        const float p0 = c.x;
        const float p1 = p0 * c.y;
        const float p2 = p1 * c.z;
        const float p3 = p2 * c.w;
        const float recv = __shfl_xor(p3, 1);
        float4 o;
        if (half == 0) {
            o.x = c.y * c.z * c.w * recv;  // wire 0: c1..c7
            o.y = p1; o.z = p2; o.w = p3;  // wires 1-3: c0..cw
        } else {
            o.x = recv * p0;               // wires 4-7: (c0..c3)*(c4..cw)
            o.y = recv * p1;
            o.z = recv * p2;
            o.w = recv * p3;
        }
        const int g  = row0 + r0 + r;
        const int b_ = g >> 9;
        const int s  = g & 511;
        *(float4*)&outp[(((size_t)b_ * HH + h) * SS + s) * DKK + half * 4] = o;
    }
}

// ---------------------------------------------------------------------------
// Kernel 2: attention, R=4 q-rows/lane — SPILL-FREE configuration.
// grid 256 = (bh 0..127) x (q-half 0..1); block 512 = 8 waves, 48KB LDS.
// Live state: qa/qb(32) + aA/aB(32) + den(4) + k/v temps(16) + addr ~= 95
// regs < 128-VGPR cap that one-arg __launch_bounds__(512) yields (R15
// measured VGPR_Count=128). R12-R15 all spilled: (512,2) capped at 56-64
// (state 95 -> 67MB scratch), R15's R=8 needed 170 at cap 128. This is the
// first spill-free run of this structure.
// Full K+V (32KB) staged; wave wv = j-slice [wv*64,+64); lane owns 4 q rows
// (L+64r). q pre-scaled by log2(e)/sqrt(8) -> exp2f. Single-pass softmax
// (bounded scores). In-LDS slot combine (48KB union with dead stage);
// normalize; row-major hid write.
// ---------------------------------------------------------------------------
__global__ __launch_bounds__(512) void k_attn(
    const float* __restrict__ qh, const float* __restrict__ kh,
    const float* __restrict__ vh, float* __restrict__ hid)
{
    __shared__ float4 smem[3072];     // 48KB: stage (2048 f4) / combine (3072)

    const int t  = threadIdx.x;       // 0..511
    const int L  = t & 63;
    const int wv = t >> 6;            // 0..7
    const int bh = blockIdx.x & 127;
    const int q0 = (blockIdx.x >> 7) * 256;   // 0 or 256

    // stage K/V (2048 f4; 4 per thread, coalesced)
    {
        const float4* kg = (const float4*)kh + (size_t)bh * 1024;
        const float4* vg = (const float4*)vh + (size_t)bh * 1024;
        smem[t]        = kg[t];
        smem[t + 512]  = kg[t + 512];
        smem[1024 + t] = vg[t];
        smem[1536 + t] = vg[t + 512];
    }

    // lane's 4 q rows, pre-scaled so exp2f(s) == exp(q.k/sqrt(8))
    const float sc = 0.51012091944f;  // log2(e)/sqrt(8)
    float4 qa[4], qb[4];
    {
        const float4* qg = (const float4*)qh + ((size_t)bh * 512 + q0) * 2;
        #pragma unroll
        for (int r = 0; r < 4; ++r) {
            float4 a = qg[(L + 64 * r) * 2];
            float4 b = qg[(L + 64 * r) * 2 + 1];
            a.x *= sc; a.y *= sc; a.z *= sc; a.w *= sc;
            b.x *= sc; b.y *= sc; b.z *= sc; b.w *= sc;
            qa[r] = a; qb[r] = b;
        }
    }
    __syncthreads();

    float4 aA[4], aB[4];
    float  den[4];
    #pragma unroll
    for (int r = 0; r < 4; ++r) {
        aA[r] = make_float4(0.f, 0.f, 0.f, 0.f);
        aB[r] = make_float4(0.f, 0.f, 0.f, 0.f);
        den[r] = 0.f;
    }

    const float4* kbase = smem + wv * 128;          // this wave's 64 j rows
    const float4* vbase = smem + 1024 + wv * 128;

    #pragma unroll 4
    for (int j = 0; j < 64; ++j) {
        const float4 k0 = kbase[2 * j];
        const float4 k1 = kbase[2 * j + 1];
        const float4 v0 = vbase[2 * j];
        const float4 v1 = vbase[2 * j + 1];
        #pragma unroll
        for (int r = 0; r < 4; ++r) {
            const float s = DOT4(qa[r], k0) + DOT4(qb[r], k1);
            const float e = exp2f(s);
            den[r] += e;
            FMA4(aA[r], e, v0);
            FMA4(aB[r], e, v1);
        }
    }
    __syncthreads();    // stage dead; smem becomes combine buffer

    // combine: slots [4][256][3] f4; waves 0-3 write, 4-7 add
    if (wv < 4) {
        #pragma unroll
        for (int r = 0; r < 4; ++r) {
            const int idx = (wv * 256 + L + 64 * r) * 3;
            smem[idx]     = aA[r];
            smem[idx + 1] = aB[r];
            smem[idx + 2] = make_float4(den[r], 0.f, 0.f, 0.f);
        }
    }
    __syncthreads();
    if (wv >= 4) {
        #pragma unroll
        for (int r = 0; r < 4; ++r) {
            const int idx = ((wv - 4) * 256 + L + 64 * r) * 3;
            float4 pa = smem[idx];
            float4 pb = smem[idx + 1];
            float4 pd = smem[idx + 2];
            ADD4(pa, aA[r]); ADD4(pb, aB[r]); pd.x += den[r];
            smem[idx]     = pa;
            smem[idx + 1] = pb;
            smem[idx + 2] = pd;
        }
    }
    __syncthreads();

    // final 4-way reduce + normalize + write (row-major hid)
    if (t < 256) {
        float4 rA = make_float4(0.f, 0.f, 0.f, 0.f), rB = rA;
        float rd = 0.f;
        #pragma unroll
        for (int s4 = 0; s4 < 4; ++s4) {
            const int idx = (s4 * 256 + t) * 3;
            const float4 a = smem[idx];
            const float4 b = smem[idx + 1];
            ADD4(rA, a); ADD4(rB, b);
            rd += smem[idx + 2].x;
        }
        const float inv = 1.0f / rd;
        rA.x *= inv; rA.y *= inv; rA.z *= inv; rA.w *= inv;
        rB.x *= inv; rB.y *= inv; rB.z *= inv; rB.w *= inv;
        const int b_ = bh >> 4, h = bh & 15;
        float* o = hid + ((size_t)(b_ * 512) + q0 + t) * 128 + h * 8;
        ((float4*)o)[0] = rA;
        ((float4*)o)[1] = rB;
    }
}

// ---------------------------------------------------------------------------
// Kernel 3: output projection hid(4096x128, row-major) @ Wo(128x128) + bo.
// grid 256 x 256: 16 rows/block (R13-proven, unchanged).
// ---------------------------------------------------------------------------
__global__ __launch_bounds__(256, 4) void k_out(
    const float* __restrict__ hid, const float* __restrict__ Wo,
    const float* __restrict__ bo, float* __restrict__ out)
{
    __shared__ float hs[16][128];
    const int t = threadIdx.x;
    const int row0 = blockIdx.x * 16;

    {
        const float4* hv = (const float4*)(hid + (size_t)row0 * 128);
        float4* hsv = (float4*)&hs[0][0];
        hsv[t]       = hv[t];
        hsv[t + 256] = hv[t + 256];
    }
    __syncthreads();

    const int cg   = t & 31;
    const int col0 = cg * 4;
    const int rg   = t >> 5;
    const int r0   = rg * 2;

    float4 acc0 = *(const float4*)&bo[col0];
    float4 acc1 = acc0;

    #pragma unroll 4
    for (int k4 = 0; k4 < 32; ++k4) {
        const float4 xa = ((const float4*)hs[r0 + 0])[k4];
        const float4 xb = ((const float4*)hs[r0 + 1])[k4];
        const float4 w0 = *(const float4*)&Wo[(k4 * 4 + 0) * 128 + col0];
        const float4 w1 = *(const float4*)&Wo[(k4 * 4 + 1) * 128 + col0];
        const float4 w2 = *(const float4*)&Wo[(k4 * 4 + 2) * 128 + col0];
        const float4 w3 = *(const float4*)&Wo[(k4 * 4 + 3) * 128 + col0];
        FMA4(acc0, xa.x, w0); FMA4(acc0, xa.y, w1);
        FMA4(acc0, xa.z, w2); FMA4(acc0, xa.w, w3);
        FMA4(acc1, xb.x, w0); FMA4(acc1, xb.y, w1);
        FMA4(acc1, xb.z, w2); FMA4(acc1, xb.w, w3);
    }

    *(float4*)&out[(size_t)(row0 + r0 + 0) * 128 + col0] = acc0;
    *(float4*)&out[(size_t)(row0 + r0 + 1) * 128 + col0] = acc1;
}

// ---------------------------------------------------------------------------
extern "C" void kernel_launch(void* const* d_in, const int* in_sizes, int n_in,
                              void* d_out, int out_size, void* d_ws, size_t ws_size,
                              hipStream_t stream)
{
    const float* x     = (const float*)d_in[0];
    const float* Wq    = (const float*)d_in[1];
    const float* bq    = (const float*)d_in[2];
    const float* Wk    = (const float*)d_in[3];
    const float* bk    = (const float*)d_in[4];
    const float* Wv    = (const float*)d_in[5];
    const float* bv    = (const float*)d_in[6];
    const float* Wo    = (const float*)d_in[7];
    const float* bo    = (const float*)d_in[8];
    const float* theta = (const float*)d_in[9];
    float* out = (float*)d_out;

    float* ws  = (float*)d_ws;
    float* qh  = ws;                   // B*H*S*8 = 524288 floats each
    float* kh  = ws + 524288;
    float* vh  = ws + 1048576;
    float* hid = ws + 1572864;         // row-major (B,S,E)

    k_qkvq<<<dim3(256, 3), 256, 0, stream>>>(x, Wq, bq, Wk, bk, Wv, bv,
                                             theta, qh, kh, vh);
    k_attn<<<256, 512, 0, stream>>>(qh, kh, vh, hid);
    k_out <<<256, 256, 0, stream>>>(hid, Wo, bo, out);
}